// Round 5
// baseline (324.495 us; speedup 1.0000x reference)
//
#include <hip/hip_runtime.h>

#define KN 12
#define DNBR 320
#define DNEW 256
#define BN_TOT 8192
#define ATB 2                 // atoms per tile (fused)
#define TPT 4                 // tiles per persistent block
#define HATB 16               // atoms per block (h_pre)
#define NKS_E 10              // 320/32
#define NKS_H 8               // 256/32
#define ASTR_H 264            // h_pre A row stride in u16 (256 + 8 pad)
#define H_OFF 294912          // byte offset of precomputed h in workspace (after B2)
#define NCHUNK 40             // fused A2 chunks: at(2) x ks(10) x half(2), 1KB each

typedef short bf8_t __attribute__((ext_vector_type(8)));
typedef float f32x4 __attribute__((ext_vector_type(4)));
typedef unsigned short us8 __attribute__((ext_vector_type(8)));
using u16 = unsigned short;
using u32 = unsigned int;

typedef __attribute__((address_space(3))) void lds_vp;
typedef __attribute__((address_space(1))) const void gc_vp;

__device__ __forceinline__ void dma16(const void* g, void* l) {
    // async global->LDS: 64 lanes x 16B, LDS dest = base + lane*16
    __builtin_amdgcn_global_load_lds((gc_vp*)g, (lds_vp*)l, 16, 0, 0);
}

__device__ __forceinline__ u16 f2bf(float f) {
    u32 x = __float_as_uint(f);
    return (u16)((x + 0x7fffu + ((x >> 16) & 1u)) >> 16);  // RNE
}

__device__ __forceinline__ us8 pack8(float4 a, float4 b) {
    us8 v;
    v[0] = f2bf(a.x); v[1] = f2bf(a.y); v[2] = f2bf(a.z); v[3] = f2bf(a.w);
    v[4] = f2bf(b.x); v[5] = f2bf(b.y); v[6] = f2bf(b.z); v[7] = f2bf(b.w);
    return v;
}

// 8 fp32 -> 8 bf16 via HW packed convert (RNE, bit-identical to f2bf; validated R2)
__device__ __forceinline__ bf8_t cvt8(float4 a, float4 b) {
    u32 r0, r1, r2, r3;
    asm("v_cvt_pk_bf16_f32 %0, %1, %2" : "=v"(r0) : "v"(a.x), "v"(a.y));
    asm("v_cvt_pk_bf16_f32 %0, %1, %2" : "=v"(r1) : "v"(a.z), "v"(a.w));
    asm("v_cvt_pk_bf16_f32 %0, %1, %2" : "=v"(r2) : "v"(b.x), "v"(b.y));
    asm("v_cvt_pk_bf16_f32 %0, %1, %2" : "=v"(r3) : "v"(b.z), "v"(b.w));
    union { u32 u[4]; bf8_t v; } cv;
    cv.u[0] = r0; cv.u[1] = r1; cv.u[2] = r2; cv.u[3] = r3;
    return cv.v;
}

// ---- kernel 1: fragment-major stacked B2: tiles 0..159 = Wn (10 ks x 16 nt),
// tiles 160..287 = Wa (8 ks x 16 nt). Tile = 64 lanes x 8 u16 (1KB). ----
__global__ __launch_bounds__(256) void build_b2(
    const float* __restrict__ Wn, const float* __restrict__ Wa,
    u16* __restrict__ B2)
{
    int tile = blockIdx.x * 4 + (threadIdx.x >> 6);   // 0..287
    int l = threadIdx.x & 63;
    int q = l >> 4, m = l & 15;
    us8 v;
    if (tile < 160) {
        int ks = tile >> 4, nt = tile & 15;
        int col = nt * 16 + m;
#pragma unroll
        for (int e = 0; e < 8; e++)
            v[e] = f2bf(Wn[(ks * 32 + q * 8 + e) * DNEW + col]);
    } else {
        int tt = tile - 160;
        int ks = tt >> 4, nt = tt & 15;
        int col = nt * 16 + m;
#pragma unroll
        for (int e = 0; e < 8; e++)
            v[e] = f2bf(Wa[(ks * 32 + q * 8 + e) * DNEW + col]);
    }
    *(us8*)&B2[(size_t)tile * 512 + l * 8] = v;
}

// ---- kernel 2: precompute h = atomf @ Wa + ba, fp32 to workspace.
// 16 atoms/block (512 blocks: 2/CU), staging loads batched for MLP. ----
__global__ __launch_bounds__(256) void h_pre(
    const float* __restrict__ atomf, const u16* __restrict__ B2,
    const float* __restrict__ ba, float* __restrict__ h_g)
{
    __shared__ u16 A[HATB * ASTR_H];   // 8448 B

    const int t = threadIdx.x;
    const int l = t & 63, w = t >> 6, q = l >> 4, m = l & 15;
    const int ab = blockIdx.x * HATB;

    // stage 16 atoms x 256 f32 -> bf16: 512 us8 chunks, 2/thread, loads batched
    const float* base = atomf + (size_t)ab * DNEW;
    float4 u0 = *(const float4*)(base + t * 8);
    float4 u1 = *(const float4*)(base + t * 8 + 4);
    float4 u2 = *(const float4*)(base + (t + 256) * 8);
    float4 u3 = *(const float4*)(base + (t + 256) * 8 + 4);
    int ai = t >> 5, c8 = t & 31;                 // (t+256)>>5 = ai+8, (t+256)&31 = c8
    *(us8*)&A[ai * ASTR_H + c8 * 8] = pack8(u0, u1);
    *(us8*)&A[(ai + 8) * ASTR_H + c8 * 8] = pack8(u2, u3);
    __syncthreads();

    f32x4 acc[4];
#pragma unroll
    for (int j = 0; j < 4; j++) acc[j] = (f32x4){0.f, 0.f, 0.f, 0.f};

#pragma unroll
    for (int ks = 0; ks < NKS_H; ks++) {
        bf8_t af = *(bf8_t*)&A[m * ASTR_H + ks * 32 + q * 8];
#pragma unroll
        for (int j = 0; j < 4; j++) {
            bf8_t bfj = *(const bf8_t*)&B2[((size_t)(160 + ks * 16 + w * 4 + j) * 64 + l) * 8];
            acc[j] = __builtin_amdgcn_mfma_f32_16x16x32_bf16(af, bfj, acc[j], 0, 0, 0);
        }
    }
#pragma unroll
    for (int j = 0; j < 4; j++) {
        int col = w * 64 + j * 16 + m;
        float bav = ba[col];
#pragma unroll
        for (int r = 0; r < 4; r++) {
            int row = ab + q * 4 + r;
            h_g[(size_t)row * DNEW + col] = acc[j][r] + bav;
        }
    }
}

// ---- kernel 3: PERSISTENT fused e-GEMM + GATv2 attention + LN.
// 1024 blocks (4/CU, one dispatch generation), each processes TPT=4 consecutive
// tiles of ATB=2 atoms. A2 DMA for tile g+1 issues during tile g's epilogue, so
// the DMA round trip is exposed only once per block. Per-tile params issue before
// the barrier (overlap DMA drain). Verified K-loop/score/softmax/LN unchanged. ----
__global__ __launch_bounds__(256, 4) void fused_all(
    const float* __restrict__ nbrf,
    const float* __restrict__ smaskg, const float* __restrict__ amaskg,
    const u16* __restrict__ B2, const float* __restrict__ h_g,
    const float* __restrict__ bnb, const float* __restrict__ walg,
    const float* __restrict__ balg, const float* __restrict__ gam,
    const float* __restrict__ bet, float* __restrict__ out)
{
    __shared__ __align__(16) float smem[NCHUNK * 256];   // 40960 B = 4 blocks/CU

    const int t = threadIdx.x;
    const int l = t & 63, w = t >> 6, q = l >> 4, m = l & 15;
    const bool qv = (q < 3);
    const int srow = (m < KN) ? m : (KN - 1);   // clamp: pad lanes re-read row 11 (masked later)

    // ---- tile-invariant params (hoisted) ----
    const float bal = balg[0];
    float bnbv[4], wv[4], gv[4], btv[4];
#pragma unroll
    for (int j = 0; j < 4; j++) {
        int col = w * 64 + j * 16 + m;
        bnbv[j] = bnb[col];
        wv[j] = walg[(j * 16 + m) & 31];
        gv[j] = gam[col];
        btv[j] = bet[col];
    }

    const int tile0 = blockIdx.x * TPT;

    // ---- issue A2 DMA for first tile ----
    {
        const int a0 = tile0 * ATB;
        for (int c = w; c < NCHUNK; c += 4) {
            int at = c / 20, rem = c - at * 20, ksc = rem >> 1, half = rem & 1;
            const float* src = nbrf + ((size_t)(a0 + at) * KN + srow) * DNBR
                             + ksc * 32 + q * 8 + half * 4;
            dma16(src, (char*)smem + (size_t)c * 1024);
        }
    }

    for (int g = 0; g < TPT; ++g) {
        const int a0 = (tile0 + g) * ATB;

        // ---- per-tile params: issued BEFORE barrier, overlap DMA drain ----
        float hv[ATB][4];
#pragma unroll
        for (int j = 0; j < 4; j++) {
            int col = w * 64 + j * 16 + m;
            hv[0][j] = h_g[(size_t)(a0 + 0) * DNEW + col];
            hv[1][j] = h_g[(size_t)(a0 + 1) * DNEW + col];
        }
        float smv[ATB][4], amv[ATB][4];
#pragma unroll
        for (int at = 0; at < ATB; at++)
#pragma unroll
            for (int r = 0; r < 4; r++) {
                int k = q * 4 + r;
                smv[at][r] = qv ? smaskg[(size_t)(a0 + at) * KN + k] + bal : 0.f;
                amv[at][r] = qv ? amaskg[(size_t)(a0 + at) * KN + k] : 0.f;
            }

        __syncthreads();   // b1: DMA drained (vmcnt(0)), A2 ready

        // ---- e-GEMM: 4 B2 global loads + 4 A2 ds_reads + 8 MFMA per ks ----
        const float4* A2 = (const float4*)smem;
        f32x4 acc_e[ATB][4];
#pragma unroll
        for (int at = 0; at < ATB; at++)
#pragma unroll
            for (int j = 0; j < 4; j++) acc_e[at][j] = (f32x4){0.f, 0.f, 0.f, 0.f};

#pragma unroll
        for (int ks = 0; ks < NKS_E; ks++) {
            bf8_t bfj[4];
#pragma unroll
            for (int j = 0; j < 4; j++)
                bfj[j] = *(const bf8_t*)&B2[((size_t)(ks * 16 + w * 4 + j) * 64 + l) * 8];
            float4 lo0 = A2[(size_t)((0 * NKS_E + ks) * 2 + 0) * 64 + l];
            float4 hi0 = A2[(size_t)((0 * NKS_E + ks) * 2 + 1) * 64 + l];
            float4 lo1 = A2[(size_t)((1 * NKS_E + ks) * 2 + 0) * 64 + l];
            float4 hi1 = A2[(size_t)((1 * NKS_E + ks) * 2 + 1) * 64 + l];
            bf8_t af0 = cvt8(lo0, hi0);
            bf8_t af1 = cvt8(lo1, hi1);
#pragma unroll
            for (int j = 0; j < 4; j++) {
                acc_e[0][j] = __builtin_amdgcn_mfma_f32_16x16x32_bf16(af0, bfj[j], acc_e[0][j], 0, 0, 0);
                acc_e[1][j] = __builtin_amdgcn_mfma_f32_16x16x32_bf16(af1, bfj[j], acc_e[1][j], 0, 0, 0);
            }
        }

        // ---- e_reg = acc_e + bnb (true e) ----
#pragma unroll
        for (int j = 0; j < 4; j++) {
#pragma unroll
            for (int at = 0; at < ATB; at++)
#pragma unroll
                for (int r = 0; r < 4; r++) acc_e[at][j][r] += bnbv[j];
        }

        // ---- scores + softmax + attn + ctx: wave-local (wave w owns heads 2w,2w+1) ----
        float ctxv[ATB][4], s1s[ATB], s2s[ATB];
#pragma unroll
        for (int at = 0; at < ATB; at++) {
            float s1 = 0.f, s2 = 0.f;
#pragma unroll
            for (int jj = 0; jj < 2; jj++) {
                float p[4];
#pragma unroll
                for (int r = 0; r < 4; r++) {
                    float pp = 0.f;
#pragma unroll
                    for (int jo = 0; jo < 2; jo++) {
                        int j = jj * 2 + jo;
                        float f = acc_e[at][j][r] + hv[at][j];
                        f = f > 0.f ? f : 0.01f * f;
                        pp = fmaf(f, wv[j], pp);
                    }
                    pp += __shfl_xor(pp, 1);
                    pp += __shfl_xor(pp, 2);
                    pp += __shfl_xor(pp, 4);
                    pp += __shfl_xor(pp, 8);
                    p[r] = qv ? pp + smv[at][r] : -1e30f;
                }
                float mx = fmaxf(fmaxf(p[0], p[1]), fmaxf(p[2], p[3]));
                mx = fmaxf(mx, __shfl_xor(mx, 16));
                mx = fmaxf(mx, __shfl_xor(mx, 32));
                float ex[4], ss = 0.f;
#pragma unroll
                for (int r = 0; r < 4; r++) {
                    ex[r] = qv ? __expf(p[r] - mx) : 0.f;
                    ss += ex[r];
                }
                ss += __shfl_xor(ss, 16);
                ss += __shfl_xor(ss, 32);
                float inv = 1.f / ss;
                float am[4];
#pragma unroll
                for (int r = 0; r < 4; r++)
                    am[r] = qv ? ex[r] * inv * amv[at][r] : 0.f;
#pragma unroll
                for (int jo = 0; jo < 2; jo++) {
                    int j = jj * 2 + jo;
                    float cp = am[0] * acc_e[at][j][0] + am[1] * acc_e[at][j][1] +
                               am[2] * acc_e[at][j][2] + am[3] * acc_e[at][j][3];
                    cp += __shfl_xor(cp, 16);
                    cp += __shfl_xor(cp, 32);
                    ctxv[at][j] = cp;
                    s1 += cp;
                    s2 += cp * cp;
                }
            }
#pragma unroll
            for (int off = 1; off < 16; off <<= 1) {
                s1 += __shfl_xor(s1, off);
                s2 += __shfl_xor(s2, off);
            }
            s1s[at] = s1; s2s[at] = s2;
        }

        // ---- LN cross-wave reduce; red_l aliases chunk0 (dead after K-loop) ----
        float* red_l = smem;   // [ATB][8]
        __syncthreads();       // b2: all waves done reading A2
        if (l == 0) {
#pragma unroll
            for (int at = 0; at < ATB; at++) {
                red_l[at * 8 + w] = s1s[at];
                red_l[at * 8 + 4 + w] = s2s[at];
            }
        }
        __syncthreads();       // b3: red_l visible

        float mu_[ATB], rs_[ATB];
#pragma unroll
        for (int at = 0; at < ATB; at++) {
            float ts1 = red_l[at * 8 + 0] + red_l[at * 8 + 1] + red_l[at * 8 + 2] + red_l[at * 8 + 3];
            float ts2 = red_l[at * 8 + 4] + red_l[at * 8 + 5] + red_l[at * 8 + 6] + red_l[at * 8 + 7];
            float mu = ts1 * (1.f / 256.f);
            float var = ts2 * (1.f / 256.f) - mu * mu;
            var = fmaxf(var, 0.f);
            mu_[at] = mu;
            rs_[at] = rsqrtf(var + 1e-5f);
        }
        __syncthreads();       // b4: red_l consumed -> chunk0 free for next DMA

        // ---- issue next tile's A2 DMA: flight overlaps LN store + loop turn ----
        if (g + 1 < TPT) {
            const int an = (tile0 + g + 1) * ATB;
            for (int c = w; c < NCHUNK; c += 4) {
                int at = c / 20, rem = c - at * 20, ksc = rem >> 1, half = rem & 1;
                const float* src = nbrf + ((size_t)(an + at) * KN + srow) * DNBR
                                 + ksc * 32 + q * 8 + half * 4;
                dma16(src, (char*)smem + (size_t)c * 1024);
            }
        }

        // ---- LayerNorm epilogue ----
        if (q == 0) {
#pragma unroll
            for (int at = 0; at < ATB; at++) {
#pragma unroll
                for (int j = 0; j < 4; j++) {
                    int col = w * 64 + j * 16 + m;
                    out[(size_t)(a0 + at) * DNEW + col] =
                        (ctxv[at][j] - mu_[at]) * rs_[at] * gv[j] + btv[j];
                }
            }
        }
    }
}

extern "C" void kernel_launch(void* const* d_in, const int* in_sizes, int n_in,
                              void* d_out, int out_size, void* d_ws, size_t ws_size,
                              hipStream_t stream) {
    const float* atomf = (const float*)d_in[0];
    const float* nbrf  = (const float*)d_in[1];
    const float* smask = (const float*)d_in[2];
    const float* amask = (const float*)d_in[3];
    const float* Wa    = (const float*)d_in[4];
    const float* ba    = (const float*)d_in[5];
    const float* Wn    = (const float*)d_in[6];
    const float* bnb   = (const float*)d_in[7];
    const float* wal   = (const float*)d_in[8];
    const float* bal   = (const float*)d_in[9];
    const float* gam   = (const float*)d_in[10];
    const float* bet   = (const float*)d_in[11];
    float* outp = (float*)d_out;

    u16* B2 = (u16*)d_ws;                              // 288 KiB
    float* h_g = (float*)((char*)d_ws + H_OFF);        // 8 MiB fp32 h

    build_b2<<<72, 256, 0, stream>>>(Wn, Wa, B2);
    h_pre<<<BN_TOT / HATB, 256, 0, stream>>>(atomf, B2, ba, h_g);
    fused_all<<<BN_TOT / (ATB * TPT), 256, 0, stream>>>(nbrf, smask, amask, B2, h_g,
                                                        bnb, wal, bal, gam, bet, outp);
}

// Round 6
// 247.866 us; speedup vs baseline: 1.3092x; 1.3092x over previous
//
#include <hip/hip_runtime.h>

#define KN 12
#define DNBR 320
#define DNEW 256
#define BN_TOT 8192
#define ATB 4                 // atoms per block (fused)
#define HATB 16               // atoms per block (h_pre)
#define NKS_E 10              // 320/32
#define NKS_H 8               // 256/32
#define ASTR_H 264            // h_pre A row stride in u16 (256 + 8 pad)
#define H_OFF 294912          // byte offset of precomputed h in workspace (after B2)
#define NCHUNK 80             // fused A2 chunks: at(4) x ks(10) x half(2), 1KB each

typedef short bf8_t __attribute__((ext_vector_type(8)));
typedef float f32x4 __attribute__((ext_vector_type(4)));
typedef unsigned short us8 __attribute__((ext_vector_type(8)));
using u16 = unsigned short;
using u32 = unsigned int;

typedef __attribute__((address_space(3))) void lds_vp;
typedef __attribute__((address_space(1))) const void gc_vp;

__device__ __forceinline__ void dma16(const void* g, void* l) {
    // async global->LDS: 64 lanes x 16B, LDS dest = base + lane*16
    __builtin_amdgcn_global_load_lds((gc_vp*)g, (lds_vp*)l, 16, 0, 0);
}

__device__ __forceinline__ u16 f2bf(float f) {
    u32 x = __float_as_uint(f);
    return (u16)((x + 0x7fffu + ((x >> 16) & 1u)) >> 16);  // RNE
}

__device__ __forceinline__ us8 pack8(float4 a, float4 b) {
    us8 v;
    v[0] = f2bf(a.x); v[1] = f2bf(a.y); v[2] = f2bf(a.z); v[3] = f2bf(a.w);
    v[4] = f2bf(b.x); v[5] = f2bf(b.y); v[6] = f2bf(b.z); v[7] = f2bf(b.w);
    return v;
}

// 8 fp32 -> 8 bf16 via HW packed convert (RNE, bit-identical to f2bf; validated R2)
__device__ __forceinline__ bf8_t cvt8(float4 a, float4 b) {
    u32 r0, r1, r2, r3;
    asm("v_cvt_pk_bf16_f32 %0, %1, %2" : "=v"(r0) : "v"(a.x), "v"(a.y));
    asm("v_cvt_pk_bf16_f32 %0, %1, %2" : "=v"(r1) : "v"(a.z), "v"(a.w));
    asm("v_cvt_pk_bf16_f32 %0, %1, %2" : "=v"(r2) : "v"(b.x), "v"(b.y));
    asm("v_cvt_pk_bf16_f32 %0, %1, %2" : "=v"(r3) : "v"(b.z), "v"(b.w));
    union { u32 u[4]; bf8_t v; } cv;
    cv.u[0] = r0; cv.u[1] = r1; cv.u[2] = r2; cv.u[3] = r3;
    return cv.v;
}

// ---- kernel 1: fragment-major stacked B2: tiles 0..159 = Wn (10 ks x 16 nt),
// tiles 160..287 = Wa (8 ks x 16 nt). Tile = 64 lanes x 8 u16 (1KB). ----
__global__ __launch_bounds__(256) void build_b2(
    const float* __restrict__ Wn, const float* __restrict__ Wa,
    u16* __restrict__ B2)
{
    int tile = blockIdx.x * 4 + (threadIdx.x >> 6);   // 0..287
    int l = threadIdx.x & 63;
    int q = l >> 4, m = l & 15;
    us8 v;
    if (tile < 160) {
        int ks = tile >> 4, nt = tile & 15;
        int col = nt * 16 + m;
#pragma unroll
        for (int e = 0; e < 8; e++)
            v[e] = f2bf(Wn[(ks * 32 + q * 8 + e) * DNEW + col]);
    } else {
        int tt = tile - 160;
        int ks = tt >> 4, nt = tt & 15;
        int col = nt * 16 + m;
#pragma unroll
        for (int e = 0; e < 8; e++)
            v[e] = f2bf(Wa[(ks * 32 + q * 8 + e) * DNEW + col]);
    }
    *(us8*)&B2[(size_t)tile * 512 + l * 8] = v;
}

// ---- kernel 2: precompute h = atomf @ Wa + ba, fp32 to workspace.
// 16 atoms/block (512 blocks: 2/CU), staging loads batched for MLP. ----
__global__ __launch_bounds__(256) void h_pre(
    const float* __restrict__ atomf, const u16* __restrict__ B2,
    const float* __restrict__ ba, float* __restrict__ h_g)
{
    __shared__ u16 A[HATB * ASTR_H];   // 8448 B

    const int t = threadIdx.x;
    const int l = t & 63, w = t >> 6, q = l >> 4, m = l & 15;
    const int ab = blockIdx.x * HATB;

    // stage 16 atoms x 256 f32 -> bf16: 512 us8 chunks, 2/thread, loads batched
    const float* base = atomf + (size_t)ab * DNEW;
    float4 u0 = *(const float4*)(base + t * 8);
    float4 u1 = *(const float4*)(base + t * 8 + 4);
    float4 u2 = *(const float4*)(base + (t + 256) * 8);
    float4 u3 = *(const float4*)(base + (t + 256) * 8 + 4);
    int ai = t >> 5, c8 = t & 31;                 // (t+256)>>5 = ai+8, (t+256)&31 = c8
    *(us8*)&A[ai * ASTR_H + c8 * 8] = pack8(u0, u1);
    *(us8*)&A[(ai + 8) * ASTR_H + c8 * 8] = pack8(u2, u3);
    __syncthreads();

    f32x4 acc[4];
#pragma unroll
    for (int j = 0; j < 4; j++) acc[j] = (f32x4){0.f, 0.f, 0.f, 0.f};

#pragma unroll
    for (int ks = 0; ks < NKS_H; ks++) {
        bf8_t af = *(bf8_t*)&A[m * ASTR_H + ks * 32 + q * 8];
#pragma unroll
        for (int j = 0; j < 4; j++) {
            bf8_t bfj = *(const bf8_t*)&B2[((size_t)(160 + ks * 16 + w * 4 + j) * 64 + l) * 8];
            acc[j] = __builtin_amdgcn_mfma_f32_16x16x32_bf16(af, bfj, acc[j], 0, 0, 0);
        }
    }
#pragma unroll
    for (int j = 0; j < 4; j++) {
        int col = w * 64 + j * 16 + m;
        float bav = ba[col];
#pragma unroll
        for (int r = 0; r < 4; r++) {
            int row = ab + q * 4 + r;
            h_g[(size_t)row * DNEW + col] = acc[j][r] + bav;
        }
    }
}

// ---- kernel 3: fused e-GEMM + GATv2 attention + LN. ATB=4 atoms/block,
// 512 threads / 8 waves; wave w owns cols [w*32, w*32+32) = exactly head w.
// Per ks each wave loads 2 B2 tiles feeding 4 atoms' MFMAs (2x amortization
// vs R3 -> B2 L2 traffic halves to 328 MB). A2 via async DMA fragment-major
// (per-lane source swizzle), 80 chunks. LDS 81920 B = 2 blocks/CU = 16 waves. ----
__global__ __launch_bounds__(512, 4) void fused_all(
    const float* __restrict__ nbrf,
    const float* __restrict__ smaskg, const float* __restrict__ amaskg,
    const u16* __restrict__ B2, const float* __restrict__ h_g,
    const float* __restrict__ bnb, const float* __restrict__ walg,
    const float* __restrict__ balg, const float* __restrict__ gam,
    const float* __restrict__ bet, float* __restrict__ out)
{
    __shared__ __align__(16) float smem[NCHUNK * 256];   // 81920 B

    const int t = threadIdx.x;
    const int l = t & 63, q = l >> 4, m = l & 15;
    const int w = __builtin_amdgcn_readfirstlane(t >> 6);   // wave id 0..7, scalarized
    const int a0 = blockIdx.x * ATB;
    const bool qv = (q < 3);
    const int srow = (m < KN) ? m : (KN - 1);   // clamp: pad lanes re-read row 11 (masked later)

    // ---- issue async A2 DMA first: 80 chunks, wave w takes c = w, w+8, ... ----
    for (int c = w; c < NCHUNK; c += 8) {
        int at = c / 20, rem = c - at * 20, ksc = rem >> 1, half = rem & 1;
        const float* src = nbrf + ((size_t)(a0 + at) * KN + srow) * DNBR
                         + ksc * 32 + q * 8 + half * 4;
        dma16(src, (char*)smem + (size_t)c * 1024);
    }

    // ---- params (issued before barrier; overlap DMA drain) ----
    const float bal = balg[0];
    float hv[ATB][2], bnbv[2], wv[2], gv[2], btv[2];
#pragma unroll
    for (int j = 0; j < 2; j++) {
        int col = w * 32 + j * 16 + m;
        bnbv[j] = bnb[col];
        wv[j] = walg[j * 16 + m];      // head-relative dim
        gv[j] = gam[col];
        btv[j] = bet[col];
#pragma unroll
        for (int at = 0; at < ATB; at++)
            hv[at][j] = h_g[(size_t)(a0 + at) * DNEW + col];
    }
    float smv[ATB][4], amv[ATB][4];
#pragma unroll
    for (int at = 0; at < ATB; at++)
#pragma unroll
        for (int r = 0; r < 4; r++) {
            int k = q * 4 + r;
            smv[at][r] = qv ? smaskg[(size_t)(a0 + at) * KN + k] + bal : 0.f;
            amv[at][r] = qv ? amaskg[(size_t)(a0 + at) * KN + k] : 0.f;
        }

    __syncthreads();   // b1: DMA drained (vmcnt(0)), A2 ready

    // ---- e-GEMM: per ks, 2 B2 tile loads feed 4 atoms (8 MFMA) ----
    const float4* A2 = (const float4*)smem;
    f32x4 acc_e[ATB][2];
#pragma unroll
    for (int at = 0; at < ATB; at++)
#pragma unroll
        for (int j = 0; j < 2; j++) acc_e[at][j] = (f32x4){0.f, 0.f, 0.f, 0.f};

#pragma unroll
    for (int ks = 0; ks < NKS_E; ks++) {
        bf8_t bfj[2];
#pragma unroll
        for (int j = 0; j < 2; j++)
            bfj[j] = *(const bf8_t*)&B2[((size_t)(ks * 16 + w * 2 + j) * 64 + l) * 8];
#pragma unroll
        for (int at = 0; at < ATB; at++) {
            float4 lo = A2[(size_t)((at * NKS_E + ks) * 2 + 0) * 64 + l];
            float4 hi = A2[(size_t)((at * NKS_E + ks) * 2 + 1) * 64 + l];
            bf8_t af = cvt8(lo, hi);
            acc_e[at][0] = __builtin_amdgcn_mfma_f32_16x16x32_bf16(af, bfj[0], acc_e[at][0], 0, 0, 0);
            acc_e[at][1] = __builtin_amdgcn_mfma_f32_16x16x32_bf16(af, bfj[1], acc_e[at][1], 0, 0, 0);
        }
    }

    // ---- e_reg = acc_e + bnb (true e) ----
#pragma unroll
    for (int j = 0; j < 2; j++)
#pragma unroll
        for (int at = 0; at < ATB; at++)
#pragma unroll
            for (int r = 0; r < 4; r++) acc_e[at][j][r] += bnbv[j];

    // ---- scores + softmax + attn + ctx: wave w owns head w, fully wave-local ----
    float ctxv[ATB][2], s1s[ATB], s2s[ATB];
#pragma unroll
    for (int at = 0; at < ATB; at++) {
        float p[4];
#pragma unroll
        for (int r = 0; r < 4; r++) {
            float pp = 0.f;
#pragma unroll
            for (int j = 0; j < 2; j++) {
                float f = acc_e[at][j][r] + hv[at][j];
                f = f > 0.f ? f : 0.01f * f;
                pp = fmaf(f, wv[j], pp);
            }
            pp += __shfl_xor(pp, 1);
            pp += __shfl_xor(pp, 2);
            pp += __shfl_xor(pp, 4);
            pp += __shfl_xor(pp, 8);
            p[r] = qv ? pp + smv[at][r] : -1e30f;
        }
        float mx = fmaxf(fmaxf(p[0], p[1]), fmaxf(p[2], p[3]));
        mx = fmaxf(mx, __shfl_xor(mx, 16));
        mx = fmaxf(mx, __shfl_xor(mx, 32));
        float ex[4], ss = 0.f;
#pragma unroll
        for (int r = 0; r < 4; r++) {
            ex[r] = qv ? __expf(p[r] - mx) : 0.f;
            ss += ex[r];
        }
        ss += __shfl_xor(ss, 16);
        ss += __shfl_xor(ss, 32);
        float inv = 1.f / ss;
        float am[4];
#pragma unroll
        for (int r = 0; r < 4; r++)
            am[r] = qv ? ex[r] * inv * amv[at][r] : 0.f;
        float s1 = 0.f, s2 = 0.f;
#pragma unroll
        for (int j = 0; j < 2; j++) {
            float cp = am[0] * acc_e[at][j][0] + am[1] * acc_e[at][j][1] +
                       am[2] * acc_e[at][j][2] + am[3] * acc_e[at][j][3];
            cp += __shfl_xor(cp, 16);
            cp += __shfl_xor(cp, 32);
            ctxv[at][j] = cp;
            s1 += cp;
            s2 += cp * cp;
        }
        // reduce over m-group -> wave total over its 32 cols (redundant per q, fine)
#pragma unroll
        for (int off = 1; off < 16; off <<= 1) {
            s1 += __shfl_xor(s1, off);
            s2 += __shfl_xor(s2, off);
        }
        s1s[at] = s1; s2s[at] = s2;
    }

    // ---- LN cross-wave reduce; red_l aliases A2 (dead after K-loop) ----
    float* red_l = smem;   // [ATB][16]: s1 at [at*16+w], s2 at [at*16+8+w]
    __syncthreads();       // b2: all waves done reading A2
    if (l == 0) {
#pragma unroll
        for (int at = 0; at < ATB; at++) {
            red_l[at * 16 + w] = s1s[at];
            red_l[at * 16 + 8 + w] = s2s[at];
        }
    }
    __syncthreads();       // b3: red_l visible

    // ---- LayerNorm epilogue ----
#pragma unroll
    for (int at = 0; at < ATB; at++) {
        float ts1 = 0.f, ts2 = 0.f;
#pragma unroll
        for (int k = 0; k < 8; k++) {
            ts1 += red_l[at * 16 + k];
            ts2 += red_l[at * 16 + 8 + k];
        }
        float mu = ts1 * (1.f / 256.f);
        float var = ts2 * (1.f / 256.f) - mu * mu;
        var = fmaxf(var, 0.f);
        float rs = rsqrtf(var + 1e-5f);
        if (q == 0) {
#pragma unroll
            for (int j = 0; j < 2; j++) {
                int col = w * 32 + j * 16 + m;
                out[(size_t)(a0 + at) * DNEW + col] =
                    (ctxv[at][j] - mu) * rs * gv[j] + btv[j];
            }
        }
    }
}

extern "C" void kernel_launch(void* const* d_in, const int* in_sizes, int n_in,
                              void* d_out, int out_size, void* d_ws, size_t ws_size,
                              hipStream_t stream) {
    const float* atomf = (const float*)d_in[0];
    const float* nbrf  = (const float*)d_in[1];
    const float* smask = (const float*)d_in[2];
    const float* amask = (const float*)d_in[3];
    const float* Wa    = (const float*)d_in[4];
    const float* ba    = (const float*)d_in[5];
    const float* Wn    = (const float*)d_in[6];
    const float* bnb   = (const float*)d_in[7];
    const float* wal   = (const float*)d_in[8];
    const float* bal   = (const float*)d_in[9];
    const float* gam   = (const float*)d_in[10];
    const float* bet   = (const float*)d_in[11];
    float* outp = (float*)d_out;

    u16* B2 = (u16*)d_ws;                              // 288 KiB
    float* h_g = (float*)((char*)d_ws + H_OFF);        // 8 MiB fp32 h

    build_b2<<<72, 256, 0, stream>>>(Wn, Wa, B2);
    h_pre<<<BN_TOT / HATB, 256, 0, stream>>>(atomf, B2, ba, h_g);
    fused_all<<<BN_TOT / ATB, 512, 0, stream>>>(nbrf, smask, amask, B2, h_g,
                                                bnb, wal, bal, gam, bet, outp);
}

// Round 7
// 246.958 us; speedup vs baseline: 1.3140x; 1.0037x over previous
//
#include <hip/hip_runtime.h>

#define KN 12
#define DNBR 320
#define DNEW 256
#define BN_TOT 8192
#define ATB 2                 // atoms per block (fused)
#define HATB 16               // atoms per block (h_pre)
#define NKS_E 10              // 320/32
#define NKS_H 8               // 256/32
#define ASTR_H 264            // h_pre A row stride in u16 (256 + 8 pad)
#define H_OFF 294912          // byte offset of precomputed h in workspace (after B2)
#define NCHUNK 40             // fused A2 chunks: at(2) x ks(10) x half(2), 1KB each
#define PFK 3                 // B2 ks-slices preloaded before the barrier

typedef short bf8_t __attribute__((ext_vector_type(8)));
typedef float f32x4 __attribute__((ext_vector_type(4)));
typedef unsigned short us8 __attribute__((ext_vector_type(8)));
using u16 = unsigned short;
using u32 = unsigned int;

typedef __attribute__((address_space(3))) void lds_vp;
typedef __attribute__((address_space(1))) const void gc_vp;

__device__ __forceinline__ void dma16(const void* g, void* l) {
    // async global->LDS: 64 lanes x 16B, LDS dest = base + lane*16
    __builtin_amdgcn_global_load_lds((gc_vp*)g, (lds_vp*)l, 16, 0, 0);
}

__device__ __forceinline__ u16 f2bf(float f) {
    u32 x = __float_as_uint(f);
    return (u16)((x + 0x7fffu + ((x >> 16) & 1u)) >> 16);  // RNE
}

__device__ __forceinline__ us8 pack8(float4 a, float4 b) {
    us8 v;
    v[0] = f2bf(a.x); v[1] = f2bf(a.y); v[2] = f2bf(a.z); v[3] = f2bf(a.w);
    v[4] = f2bf(b.x); v[5] = f2bf(b.y); v[6] = f2bf(b.z); v[7] = f2bf(b.w);
    return v;
}

// 8 fp32 -> 8 bf16 via HW packed convert (RNE, bit-identical to f2bf; validated R2)
__device__ __forceinline__ bf8_t cvt8(float4 a, float4 b) {
    u32 r0, r1, r2, r3;
    asm("v_cvt_pk_bf16_f32 %0, %1, %2" : "=v"(r0) : "v"(a.x), "v"(a.y));
    asm("v_cvt_pk_bf16_f32 %0, %1, %2" : "=v"(r1) : "v"(a.z), "v"(a.w));
    asm("v_cvt_pk_bf16_f32 %0, %1, %2" : "=v"(r2) : "v"(b.x), "v"(b.y));
    asm("v_cvt_pk_bf16_f32 %0, %1, %2" : "=v"(r3) : "v"(b.z), "v"(b.w));
    union { u32 u[4]; bf8_t v; } cv;
    cv.u[0] = r0; cv.u[1] = r1; cv.u[2] = r2; cv.u[3] = r3;
    return cv.v;
}

// ---- kernel 1: fragment-major stacked B2: tiles 0..159 = Wn (10 ks x 16 nt),
// tiles 160..287 = Wa (8 ks x 16 nt). Tile = 64 lanes x 8 u16 (1KB). ----
__global__ __launch_bounds__(256) void build_b2(
    const float* __restrict__ Wn, const float* __restrict__ Wa,
    u16* __restrict__ B2)
{
    int tile = blockIdx.x * 4 + (threadIdx.x >> 6);   // 0..287
    int l = threadIdx.x & 63;
    int q = l >> 4, m = l & 15;
    us8 v;
    if (tile < 160) {
        int ks = tile >> 4, nt = tile & 15;
        int col = nt * 16 + m;
#pragma unroll
        for (int e = 0; e < 8; e++)
            v[e] = f2bf(Wn[(ks * 32 + q * 8 + e) * DNEW + col]);
    } else {
        int tt = tile - 160;
        int ks = tt >> 4, nt = tt & 15;
        int col = nt * 16 + m;
#pragma unroll
        for (int e = 0; e < 8; e++)
            v[e] = f2bf(Wa[(ks * 32 + q * 8 + e) * DNEW + col]);
    }
    *(us8*)&B2[(size_t)tile * 512 + l * 8] = v;
}

// ---- kernel 2: precompute h = atomf @ Wa + ba, fp32 to workspace.
// 16 atoms/block (512 blocks: 2/CU), staging loads batched for MLP. ----
__global__ __launch_bounds__(256) void h_pre(
    const float* __restrict__ atomf, const u16* __restrict__ B2,
    const float* __restrict__ ba, float* __restrict__ h_g)
{
    __shared__ u16 A[HATB * ASTR_H];   // 8448 B

    const int t = threadIdx.x;
    const int l = t & 63, w = t >> 6, q = l >> 4, m = l & 15;
    const int ab = blockIdx.x * HATB;

    // stage 16 atoms x 256 f32 -> bf16: 512 us8 chunks, 2/thread, loads batched
    const float* base = atomf + (size_t)ab * DNEW;
    float4 u0 = *(const float4*)(base + t * 8);
    float4 u1 = *(const float4*)(base + t * 8 + 4);
    float4 u2 = *(const float4*)(base + (t + 256) * 8);
    float4 u3 = *(const float4*)(base + (t + 256) * 8 + 4);
    int ai = t >> 5, c8 = t & 31;                 // (t+256)>>5 = ai+8, (t+256)&31 = c8
    *(us8*)&A[ai * ASTR_H + c8 * 8] = pack8(u0, u1);
    *(us8*)&A[(ai + 8) * ASTR_H + c8 * 8] = pack8(u2, u3);
    __syncthreads();

    f32x4 acc[4];
#pragma unroll
    for (int j = 0; j < 4; j++) acc[j] = (f32x4){0.f, 0.f, 0.f, 0.f};

#pragma unroll
    for (int ks = 0; ks < NKS_H; ks++) {
        bf8_t af = *(bf8_t*)&A[m * ASTR_H + ks * 32 + q * 8];
#pragma unroll
        for (int j = 0; j < 4; j++) {
            bf8_t bfj = *(const bf8_t*)&B2[((size_t)(160 + ks * 16 + w * 4 + j) * 64 + l) * 8];
            acc[j] = __builtin_amdgcn_mfma_f32_16x16x32_bf16(af, bfj, acc[j], 0, 0, 0);
        }
    }
#pragma unroll
    for (int j = 0; j < 4; j++) {
        int col = w * 64 + j * 16 + m;
        float bav = ba[col];
#pragma unroll
        for (int r = 0; r < 4; r++) {
            int row = ab + q * 4 + r;
            h_g[(size_t)row * DNEW + col] = acc[j][r] + bav;
        }
    }
}

// ---- kernel 3: fused e-GEMM + GATv2 attention + LN. 2 atoms/block.
// COALESCED DMA: chunk c = (at*10+ks)*2+h covers 16 rows (clamped to 12) x one
// 64B row-segment [ks*128 + h*64, +64). Lane l = (cc=l>>4, m=l&15) reads row
// min(m,11), granule cc of that segment -> per-instr source set = 12 rows x 64B
// CONTIGUOUS (12 line touches vs 48 scattered in R3). LDS granule-major
// idx = cc*16+m. K-loop read: lo = chunk(at,ks,q>>1) + (q&1)*512 + m*16,
// hi = lo+256B (2-way bank alias = free).
// B2 PRELOAD: first PFK ks-slices of B2 fragments loaded BEFORE __syncthreads
// -- barrier is a memory fence, so these loads are pinned (scheduler cannot
// re-sink them, unlike R4) and drain with the DMA's vmcnt(0). ----
__global__ __launch_bounds__(256, 4) void fused_all(
    const float* __restrict__ nbrf,
    const float* __restrict__ smaskg, const float* __restrict__ amaskg,
    const u16* __restrict__ B2, const float* __restrict__ h_g,
    const float* __restrict__ bnb, const float* __restrict__ walg,
    const float* __restrict__ balg, const float* __restrict__ gam,
    const float* __restrict__ bet, float* __restrict__ out)
{
    __shared__ __align__(16) float smem[NCHUNK * 256];   // 40960 B = 4 blocks/CU

    const int t = threadIdx.x;
    const int l = t & 63, w = t >> 6, q = l >> 4, m = l & 15;
    const int a0 = blockIdx.x * ATB;
    const bool qv = (q < 3);
    const bf8_t* B2v = (const bf8_t*)B2;

    // ---- B2 preload: pinned by the barrier (cannot be sunk past it) ----
    bf8_t pf[PFK][4];
#pragma unroll
    for (int ks = 0; ks < PFK; ks++)
#pragma unroll
        for (int j = 0; j < 4; j++)
            pf[ks][j] = B2v[(size_t)(ks * 16 + w * 4 + j) * 64 + l];

    // ---- issue async A2 DMA: 40 chunks, wave w takes c = w, w+4, ... ----
    const int cc = l >> 4;                      // granule column 0..3
    const int srow = (m < KN) ? m : (KN - 1);   // clamp: pad lanes re-read row 11 (masked later)
    for (int c = w; c < NCHUNK; c += 4) {
        int at = c / 20, rem = c - at * 20, ks = rem >> 1, h = rem & 1;
        const float* src = nbrf + ((size_t)(a0 + at) * KN + srow) * DNBR
                         + ks * 32 + h * 16 + cc * 4;
        dma16(src, (char*)smem + (size_t)c * 1024);
    }

    // ---- params (issued before barrier; overlap DMA drain) ----
    const float bal = balg[0];
    float hv[ATB][4], bnbv[4], wv[4];
#pragma unroll
    for (int j = 0; j < 4; j++) {
        int col = w * 64 + j * 16 + m;
        hv[0][j] = h_g[(size_t)(a0 + 0) * DNEW + col];
        hv[1][j] = h_g[(size_t)(a0 + 1) * DNEW + col];
        bnbv[j] = bnb[col];
        wv[j] = walg[(j * 16 + m) & 31];
    }
    float smv[ATB][4], amv[ATB][4];
#pragma unroll
    for (int at = 0; at < ATB; at++)
#pragma unroll
        for (int r = 0; r < 4; r++) {
            int k = q * 4 + r;
            smv[at][r] = qv ? smaskg[(size_t)(a0 + at) * KN + k] + bal : 0.f;
            amv[at][r] = qv ? amaskg[(size_t)(a0 + at) * KN + k] : 0.f;
        }

    __syncthreads();   // b1: DMA + preloads drained (vmcnt(0)), A2 ready

    // ---- e-GEMM ----
    const float4* A2 = (const float4*)smem;
    const int aoff = (q & 1) * 32 + m;          // float4 index within chunk
    const int hsel = q >> 1;

    f32x4 acc_e[ATB][4];
#pragma unroll
    for (int at = 0; at < ATB; at++)
#pragma unroll
        for (int j = 0; j < 4; j++) acc_e[at][j] = (f32x4){0.f, 0.f, 0.f, 0.f};

#pragma unroll
    for (int ks = 0; ks < NKS_E; ks++) {
        bf8_t bfj[4];
        if (ks < PFK) {
#pragma unroll
            for (int j = 0; j < 4; j++) bfj[j] = pf[ks][j];
        } else {
#pragma unroll
            for (int j = 0; j < 4; j++)
                bfj[j] = B2v[(size_t)(ks * 16 + w * 4 + j) * 64 + l];
        }
        int c0 = ((0 * NKS_E + ks) * 2 + hsel) * 64 + aoff;
        int c1 = ((1 * NKS_E + ks) * 2 + hsel) * 64 + aoff;
        float4 lo0 = A2[c0], hi0 = A2[c0 + 16];
        float4 lo1 = A2[c1], hi1 = A2[c1 + 16];
        bf8_t af0 = cvt8(lo0, hi0);
        bf8_t af1 = cvt8(lo1, hi1);
#pragma unroll
        for (int j = 0; j < 4; j++) {
            acc_e[0][j] = __builtin_amdgcn_mfma_f32_16x16x32_bf16(af0, bfj[j], acc_e[0][j], 0, 0, 0);
            acc_e[1][j] = __builtin_amdgcn_mfma_f32_16x16x32_bf16(af1, bfj[j], acc_e[1][j], 0, 0, 0);
        }
    }

    // ---- e_reg = acc_e + bnb (true e) ----
#pragma unroll
    for (int j = 0; j < 4; j++) {
#pragma unroll
        for (int at = 0; at < ATB; at++)
#pragma unroll
            for (int r = 0; r < 4; r++) acc_e[at][j][r] += bnbv[j];
    }

    // ---- scores + softmax + attn + ctx: wave-local (wave w owns heads 2w,2w+1) ----
    float ctxv[ATB][4], s1s[ATB], s2s[ATB];
#pragma unroll
    for (int at = 0; at < ATB; at++) {
        float s1 = 0.f, s2 = 0.f;
#pragma unroll
        for (int jj = 0; jj < 2; jj++) {
            float p[4];
#pragma unroll
            for (int r = 0; r < 4; r++) {
                float pp = 0.f;
#pragma unroll
                for (int jo = 0; jo < 2; jo++) {
                    int j = jj * 2 + jo;
                    float f = acc_e[at][j][r] + hv[at][j];
                    f = f > 0.f ? f : 0.01f * f;
                    pp = fmaf(f, wv[j], pp);
                }
                pp += __shfl_xor(pp, 1);
                pp += __shfl_xor(pp, 2);
                pp += __shfl_xor(pp, 4);
                pp += __shfl_xor(pp, 8);
                p[r] = qv ? pp + smv[at][r] : -1e30f;
            }
            float mx = fmaxf(fmaxf(p[0], p[1]), fmaxf(p[2], p[3]));
            mx = fmaxf(mx, __shfl_xor(mx, 16));
            mx = fmaxf(mx, __shfl_xor(mx, 32));
            float ex[4], ss = 0.f;
#pragma unroll
            for (int r = 0; r < 4; r++) {
                ex[r] = qv ? __expf(p[r] - mx) : 0.f;
                ss += ex[r];
            }
            ss += __shfl_xor(ss, 16);
            ss += __shfl_xor(ss, 32);
            float inv = 1.f / ss;
            float am[4];
#pragma unroll
            for (int r = 0; r < 4; r++)
                am[r] = qv ? ex[r] * inv * amv[at][r] : 0.f;
#pragma unroll
            for (int jo = 0; jo < 2; jo++) {
                int j = jj * 2 + jo;
                float cp = am[0] * acc_e[at][j][0] + am[1] * acc_e[at][j][1] +
                           am[2] * acc_e[at][j][2] + am[3] * acc_e[at][j][3];
                cp += __shfl_xor(cp, 16);
                cp += __shfl_xor(cp, 32);
                ctxv[at][j] = cp;
                s1 += cp;
                s2 += cp * cp;
            }
        }
#pragma unroll
        for (int off = 1; off < 16; off <<= 1) {
            s1 += __shfl_xor(s1, off);
            s2 += __shfl_xor(s2, off);
        }
        s1s[at] = s1; s2s[at] = s2;
    }

    // ---- LN cross-wave reduce; red_l aliases A2 (dead after K-loop) ----
    float* red_l = smem;   // [ATB][8]
    __syncthreads();       // b2: all waves done reading A2
    if (l == 0) {
#pragma unroll
        for (int at = 0; at < ATB; at++) {
            red_l[at * 8 + w] = s1s[at];
            red_l[at * 8 + 4 + w] = s2s[at];
        }
    }
    __syncthreads();       // b3: red_l visible

    // ---- LayerNorm epilogue ----
#pragma unroll
    for (int at = 0; at < ATB; at++) {
        float ts1 = red_l[at * 8 + 0] + red_l[at * 8 + 1] + red_l[at * 8 + 2] + red_l[at * 8 + 3];
        float ts2 = red_l[at * 8 + 4] + red_l[at * 8 + 5] + red_l[at * 8 + 6] + red_l[at * 8 + 7];
        float mu = ts1 * (1.f / 256.f);
        float var = ts2 * (1.f / 256.f) - mu * mu;
        var = fmaxf(var, 0.f);
        float rs = rsqrtf(var + 1e-5f);
        if (q == 0) {
#pragma unroll
            for (int j = 0; j < 4; j++) {
                int col = w * 64 + j * 16 + m;
                out[(size_t)(a0 + at) * DNEW + col] =
                    (ctxv[at][j] - mu) * rs * gam[col] + bet[col];
            }
        }
    }
}

extern "C" void kernel_launch(void* const* d_in, const int* in_sizes, int n_in,
                              void* d_out, int out_size, void* d_ws, size_t ws_size,
                              hipStream_t stream) {
    const float* atomf = (const float*)d_in[0];
    const float* nbrf  = (const float*)d_in[1];
    const float* smask = (const float*)d_in[2];
    const float* amask = (const float*)d_in[3];
    const float* Wa    = (const float*)d_in[4];
    const float* ba    = (const float*)d_in[5];
    const float* Wn    = (const float*)d_in[6];
    const float* bnb   = (const float*)d_in[7];
    const float* wal   = (const float*)d_in[8];
    const float* bal   = (const float*)d_in[9];
    const float* gam   = (const float*)d_in[10];
    const float* bet   = (const float*)d_in[11];
    float* outp = (float*)d_out;

    u16* B2 = (u16*)d_ws;                              // 288 KiB
    float* h_g = (float*)((char*)d_ws + H_OFF);        // 8 MiB fp32 h

    build_b2<<<72, 256, 0, stream>>>(Wn, Wa, B2);
    h_pre<<<BN_TOT / HATB, 256, 0, stream>>>(atomf, B2, ba, h_g);
    fused_all<<<BN_TOT / ATB, 256, 0, stream>>>(nbrf, smask, amask, B2, h_g,
                                                bnb, wal, bal, gam, bet, outp);
}